// Round 5
// baseline (2024.490 us; speedup 1.0000x reference)
//
#include <hip/hip_runtime.h>

// Problem constants
#define NB   64      // batch
#define CIN  8
#define LIN  8192
#define L1N  4096    // conv1 out length
#define T2   2048    // conv2 out length (time steps)
#define ENC  64
#define NK   128     // codebook size
#define CD   64      // code dim
#define G3   192     // 3*ENC

// d_out layout (floats): quant_z [64*2048*64] | pred [64*2048*64] | codes [64*2048]
#define QOFF 0
#define POFF 8388608
#define COFF 16777216

// ws layout (floats): cnorm[128] @0 | PC[128*192] @128 | codes_i[131072] (int) @24704
#define PCOFF 128
#define CIOFF 24704

__device__ __forceinline__ float sigf(float x) {
  float e = __builtin_amdgcn_exp2f(-1.4426950408889634f * x);
  return __builtin_amdgcn_rcpf(1.0f + e);
}
__device__ __forceinline__ float tanhf_fast(float x) {
  float e = __builtin_amdgcn_exp2f(2.8853900817779268f * x);
  return 1.0f - 2.0f * __builtin_amdgcn_rcpf(e + 1.0f);
}
__device__ __forceinline__ float rlane(float v, int k) {
  return __int_as_float(__builtin_amdgcn_readlane(__float_as_int(v), k));
}

// ---------------- K0: codebook row norms ----------------
__global__ void cnorm_kernel(const float* __restrict__ cb, float* __restrict__ cnorm) {
  int c = threadIdx.x;  // 128 threads
  const float4* r = (const float4*)(cb + c * CD);
  float s0 = 0.f, s1 = 0.f, s2 = 0.f, s3 = 0.f;
#pragma unroll
  for (int q = 0; q < 16; q += 4) {
    float4 a = r[q], b = r[q + 1], cc = r[q + 2], d = r[q + 3];
    s0 += a.x * a.x + a.y * a.y + a.z * a.z + a.w * a.w;
    s1 += b.x * b.x + b.y * b.y + b.z * b.z + b.w * b.w;
    s2 += cc.x * cc.x + cc.y * cc.y + cc.z * cc.z + cc.w * cc.w;
    s3 += d.x * d.x + d.y * d.y + d.z * d.z + d.w * d.w;
  }
  cnorm[c] = (s0 + s1) + (s2 + s3);
}

// ---------------- K1: conv1 + relu  (x[64,8,8192] -> y1[64,32,4096]) ----------------
__global__ __launch_bounds__(256) void conv1_kernel(const float* __restrict__ x,
                                                    const float* __restrict__ w1,
                                                    const float* __restrict__ b1,
                                                    float* __restrict__ y1) {
  __shared__ float sw[1280];      // [co][ci][k] natural
  __shared__ float sx[8][136];    // u = xi - (2*t0-2), u in [0,131)
  int b = blockIdx.x >> 6;
  int t0 = (blockIdx.x & 63) * 64;
  int tid = threadIdx.x;
  for (int i = tid; i < 1280; i += 256) sw[i] = w1[i];
  const float* xb = x + b * CIN * LIN;
  for (int i = tid; i < 8 * 131; i += 256) {
    int ci = i / 131, u = i - ci * 131;
    int xi = 2 * t0 - 2 + u;
    sx[ci][u] = ((unsigned)xi < (unsigned)LIN) ? xb[ci * LIN + xi] : 0.f;
  }
  __syncthreads();
  int co = tid >> 3, tg = tid & 7;
  float bias = b1[co];
  float acc[8];
#pragma unroll
  for (int j = 0; j < 8; j++) acc[j] = bias;
#pragma unroll
  for (int ci = 0; ci < 8; ci++) {
    float xv[20];
    const float2* s2 = (const float2*)(&sx[ci][16 * tg]);
#pragma unroll
    for (int q = 0; q < 10; q++) {
      float2 v = s2[q];
      xv[2 * q] = v.x; xv[2 * q + 1] = v.y;
    }
    float wk[5];
#pragma unroll
    for (int k = 0; k < 5; k++) wk[k] = sw[(co * 8 + ci) * 5 + k];
#pragma unroll
    for (int j = 0; j < 8; j++) {
#pragma unroll
      for (int k = 0; k < 5; k++) acc[j] = fmaf(xv[2 * j + k], wk[k], acc[j]);
    }
  }
  float4* outp = (float4*)(y1 + (b * 32 + co) * L1N + t0 + tg * 8);
  float4 o0, o1;
  o0.x = fmaxf(acc[0], 0.f); o0.y = fmaxf(acc[1], 0.f);
  o0.z = fmaxf(acc[2], 0.f); o0.w = fmaxf(acc[3], 0.f);
  o1.x = fmaxf(acc[4], 0.f); o1.y = fmaxf(acc[5], 0.f);
  o1.z = fmaxf(acc[6], 0.f); o1.w = fmaxf(acc[7], 0.f);
  outp[0] = o0; outp[1] = o1;
}

// ---------------- K2: conv2 + relu, transposed out (y1[64,32,4096] -> z[64,2048,64]) ----------------
__global__ void conv2_kernel(const float* __restrict__ y1, const float* __restrict__ w2,
                             const float* __restrict__ b2, float* __restrict__ z) {
  __shared__ float sw[32 * 5 * 64];
  __shared__ float sx[32][136];
  int b = blockIdx.x >> 5;
  int t0 = (blockIdx.x & 31) * 64;
  int tid = threadIdx.x;
  for (int i = tid; i < 32 * 5 * 64; i += 256) {
    int co = i & 63, r = i >> 6;
    sw[i] = w2[co * 160 + r];
  }
  for (int i = tid; i < 32 * 136; i += 256) {
    int ci = i / 136, u = i - ci * 136;
    int xi = 2 * t0 - 4 + u;
    float v = 0.f;
    if (xi >= 0 && xi < L1N) v = y1[(b * 32 + ci) * L1N + xi];
    sx[ci][u] = v;
  }
  __syncthreads();
  int co = tid & 63, ts = tid >> 6;
  float acc[16];
  float bb = b2[co];
#pragma unroll
  for (int i = 0; i < 16; i++) acc[i] = bb;
  for (int ci = 0; ci < 32; ci++) {
    float xr[40];
    const float4* sx4 = (const float4*)(&sx[ci][32 * ts]);
#pragma unroll
    for (int q = 0; q < 10; q++) {
      float4 v = sx4[q];
      xr[4 * q] = v.x; xr[4 * q + 1] = v.y; xr[4 * q + 2] = v.z; xr[4 * q + 3] = v.w;
    }
    float wk[5];
#pragma unroll
    for (int k = 0; k < 5; k++) wk[k] = sw[(ci * 5 + k) * 64 + co];
#pragma unroll
    for (int i = 0; i < 16; i++) {
#pragma unroll
      for (int k = 0; k < 5; k++) acc[i] = fmaf(xr[2 * i + k + 2], wk[k], acc[i]);
    }
  }
#pragma unroll
  for (int i = 0; i < 16; i++) {
    int t = t0 + ts * 16 + i;
    z[(b * T2 + t) * ENC + co] = fmaxf(acc[i], 0.f);
  }
}

// ---------------- K3: VQ argmin + gather — registers pinned via waves_per_eu ----------------
__global__ __attribute__((amdgpu_flat_work_group_size(256, 256), amdgpu_waves_per_eu(1, 2)))
void quant_kernel(const float* __restrict__ z,
                  const float* __restrict__ cb,
                  const float* __restrict__ cnorm,
                  float* __restrict__ quant,
                  float* __restrict__ codes_f,
                  int* __restrict__ codes_i) {
  int tid = threadIdx.x, lane = tid & 63, wave = tid >> 6;
  int vbase = blockIdx.x * 64 + wave * 16;
  float4 ca[16], cq[16];
  const float4* pa = (const float4*)(cb + lane * CD);
  const float4* pb = (const float4*)(cb + (64 + lane) * CD);
#define LQ(q) ca[q] = pa[q]; cq[q] = pb[q];
  LQ(0) LQ(1) LQ(2) LQ(3) LQ(4) LQ(5) LQ(6) LQ(7)
  LQ(8) LQ(9) LQ(10) LQ(11) LQ(12) LQ(13) LQ(14) LQ(15)
#undef LQ
  float cn0 = cnorm[lane], cn1 = cnorm[64 + lane];
  for (int v = vbase; v < vbase + 16; v++) {
    float zz = z[v * 64 + lane];
    float d00 = 0.f, d01 = 0.f, d02 = 0.f, d03 = 0.f;
    float d10 = 0.f, d11 = 0.f, d12 = 0.f, d13 = 0.f;
#define DQ(q) { \
    float h0 = rlane(zz, 4 * (q) + 0); float h1 = rlane(zz, 4 * (q) + 1); \
    float h2 = rlane(zz, 4 * (q) + 2); float h3 = rlane(zz, 4 * (q) + 3); \
    d00 = fmaf(ca[q].x, h0, d00); d01 = fmaf(ca[q].y, h1, d01); \
    d02 = fmaf(ca[q].z, h2, d02); d03 = fmaf(ca[q].w, h3, d03); \
    d10 = fmaf(cq[q].x, h0, d10); d11 = fmaf(cq[q].y, h1, d11); \
    d12 = fmaf(cq[q].z, h2, d12); d13 = fmaf(cq[q].w, h3, d13); }
    DQ(0) DQ(1) DQ(2) DQ(3) DQ(4) DQ(5) DQ(6) DQ(7)
    DQ(8) DQ(9) DQ(10) DQ(11) DQ(12) DQ(13) DQ(14) DQ(15)
#undef DQ
    float s0 = cn0 - 2.f * ((d00 + d01) + (d02 + d03));
    float s1 = cn1 - 2.f * ((d10 + d11) + (d12 + d13));
    float sc; int idx;
    if (s1 < s0) { sc = s1; idx = 64 + lane; } else { sc = s0; idx = lane; }
#pragma unroll
    for (int m = 1; m < 64; m <<= 1) {
      float os = __shfl_xor(sc, m);
      int oi = __shfl_xor(idx, m);
      if (os < sc || (os == sc && oi < idx)) { sc = os; idx = oi; }
    }
    if (lane == 0) { codes_f[v] = (float)idx; codes_i[v] = idx; }
    quant[v * 64 + lane] = cb[idx * 64 + lane];
  }
}

// ---------------- K4: PC[c][j] = b_ih[j] + sum_d cb[c][d]*w_ih[j][d]  (128x192) ----------------
__global__ __launch_bounds__(192) void pc_kernel(const float* __restrict__ cb,
                                                 const float* __restrict__ w_ih,
                                                 const float* __restrict__ b_ih,
                                                 float* __restrict__ PC) {
  int c = blockIdx.x, j = threadIdx.x;
  const float4* wp = (const float4*)(w_ih + j * ENC);
  const float4* cp = (const float4*)(cb + c * CD);
  float a0 = b_ih[j], a1 = 0.f, a2 = 0.f, a3 = 0.f;
#pragma unroll
  for (int q = 0; q < 16; q += 4) {
    float4 w0 = wp[q], c0 = cp[q];
    float4 w1 = wp[q + 1], c1 = cp[q + 1];
    float4 w2 = wp[q + 2], c2 = cp[q + 2];
    float4 w3 = wp[q + 3], c3 = cp[q + 3];
    a0 += w0.x * c0.x + w0.y * c0.y + w0.z * c0.z + w0.w * c0.w;
    a1 += w1.x * c1.x + w1.y * c1.y + w1.z * c1.z + w1.w * c1.w;
    a2 += w2.x * c2.x + w2.y * c2.y + w2.z * c2.z + w2.w * c2.w;
    a3 += w3.x * c3.x + w3.y * c3.y + w3.z * c3.z + w3.w * c3.w;
  }
  PC[c * G3 + j] = (a0 + a1) + (a2 + a3);
}

// ---------------- K5: GRU scan — 2-wave K-split, <=128 live floats/lane (no spill) ----------------
// Wave w owns k in [32w, 32w+32). Lane j keeps the k-half of W_hh rows j / 64+j / 128+j
// (96 floats). h broadcast via readlane (SGPR lane-select = 32w+m). Partial sums meet in
// LDS (double-buffered by parity, conflict-free), ONE raw lgkmcnt barrier per step; gate
// math redundant in both waves (identical h), ctx stored by wave 0 (256B-coalesced).
__global__ __attribute__((amdgpu_flat_work_group_size(128, 128), amdgpu_waves_per_eu(1, 1)))
void gru_kernel(const float* __restrict__ PC,
                const int* __restrict__ codes_i,
                const float* __restrict__ w_hh,
                const float* __restrict__ b_hh,
                float* __restrict__ ctx) {
  __shared__ float pre[2][3][2][64];   // [parity][gate][wave][j]
  int b = blockIdx.x;
  int tid = threadIdx.x;
  int w = tid >> 6, j = tid & 63;
  int kb = 32 * w;                      // this wave's k base (SGPR)
  float4 wr[8], wz[8], wn[8];
  const float4* p0 = (const float4*)(w_hh + j * ENC + kb);
  const float4* p1 = (const float4*)(w_hh + (64 + j) * ENC + kb);
  const float4* p2 = (const float4*)(w_hh + (128 + j) * ENC + kb);
#define LDW(q) wr[q] = p0[q]; wz[q] = p1[q]; wn[q] = p2[q];
  LDW(0) LDW(1) LDW(2) LDW(3) LDW(4) LDW(5) LDW(6) LDW(7)
#undef LDW
  float br = b_hh[j], bz = b_hh[64 + j], bn = b_hh[128 + j];
  const int* cp = codes_i + b * T2;
  float hreg = 0.f;
  // x pipeline 2-deep: consume x(t), hold x(t+1), load x(t+2) via prefetched code cA
  int cA = cp[2];
  float xr0, xz0, xn0, xr1, xz1, xn1;
  {
    const float* g = PC + cp[0] * G3;
    xr0 = g[j]; xz0 = g[64 + j]; xn0 = g[128 + j];
    g = PC + cp[1] * G3;
    xr1 = g[j]; xz1 = g[64 + j]; xn1 = g[128 + j];
  }
  float* cbase = ctx + (size_t)b * T2 * ENC + j;
#pragma unroll 1
  for (int t = 0; t < T2; t++) {
    int par = t & 1;
    const float* g = PC + cA * G3;                  // x for step t+2
    float xr2 = g[j], xz2 = g[64 + j], xn2 = g[128 + j];
    int tn = t + 3; if (tn > T2 - 1) tn = T2 - 1;
    cA = cp[tn];
    // partial matvec over this wave's k-half
    float fr0 = 0.f, fr1 = 0.f, fr2 = 0.f, fr3 = 0.f;
    float fz0 = 0.f, fz1 = 0.f, fz2 = 0.f, fz3 = 0.f;
    float fn0 = 0.f, fn1 = 0.f, fn2 = 0.f, fn3 = 0.f;
#define MV(q) { \
    float h0 = rlane(hreg, kb + 4 * (q) + 0); float h1 = rlane(hreg, kb + 4 * (q) + 1); \
    float h2 = rlane(hreg, kb + 4 * (q) + 2); float h3 = rlane(hreg, kb + 4 * (q) + 3); \
    fr0 = fmaf(wr[q].x, h0, fr0); fr1 = fmaf(wr[q].y, h1, fr1); \
    fr2 = fmaf(wr[q].z, h2, fr2); fr3 = fmaf(wr[q].w, h3, fr3); \
    fz0 = fmaf(wz[q].x, h0, fz0); fz1 = fmaf(wz[q].y, h1, fz1); \
    fz2 = fmaf(wz[q].z, h2, fz2); fz3 = fmaf(wz[q].w, h3, fz3); \
    fn0 = fmaf(wn[q].x, h0, fn0); fn1 = fmaf(wn[q].y, h1, fn1); \
    fn2 = fmaf(wn[q].z, h2, fn2); fn3 = fmaf(wn[q].w, h3, fn3); }
    MV(0) MV(1) MV(2) MV(3) MV(4) MV(5) MV(6) MV(7)
#undef MV
    pre[par][0][w][j] = (fr0 + fr1) + (fr2 + fr3);
    pre[par][1][w][j] = (fz0 + fz1) + (fz2 + fz3);
    pre[par][2][w][j] = (fn0 + fn1) + (fn2 + fn3);
    // LDS-only barrier: no vmcnt(0) drain (x prefetch + ctx stores stay in flight)
    asm volatile("s_waitcnt lgkmcnt(0)\n\ts_barrier" ::: "memory");
    float ghr = br + pre[par][0][0][j] + pre[par][0][1][j];
    float ghz = bz + pre[par][1][0][j] + pre[par][1][1][j];
    float ghn = bn + pre[par][2][0][j] + pre[par][2][1][j];
    float r = sigf(xr0 + ghr);
    float zg = sigf(xz0 + ghz);
    float n = tanhf_fast(xn0 + r * ghn);
    hreg = fmaf(zg, hreg - n, n);
    if (w == 0) cbase[(size_t)t * ENC] = hreg;
    xr0 = xr1; xz0 = xz1; xn0 = xn1;
    xr1 = xr2; xz1 = xz2; xn1 = xn2;
  }
}

// ---------------- K6: pred = ctx @ proj_w^T + proj_b (in-place on the ctx/pred slot) ----------------
__global__ void proj_kernel(const float* __restrict__ proj_w, const float* __restrict__ proj_b,
                            float* __restrict__ predio) {
  __shared__ float sc[64 * 64];
  int vbase = blockIdx.x * 64;
  int tid = threadIdx.x;
  int j = tid & 63, s = tid >> 6;
  for (int i = tid; i < 4096; i += 256) sc[i] = predio[vbase * 64 + i];
  __syncthreads();
  float4 w[16];
  const float4* wr = (const float4*)(proj_w + j * ENC);
#pragma unroll
  for (int q = 0; q < 16; q++) w[q] = wr[q];
  float bias = proj_b[j];
  float out[16];
#pragma unroll 4
  for (int i = 0; i < 16; i++) {
    const float4* c4 = (const float4*)(&sc[(s * 16 + i) * 64]);
    float a0 = bias, a1 = 0.f, a2 = 0.f, a3 = 0.f;
#pragma unroll
    for (int q = 0; q < 16; q += 4) {
      float4 ha = c4[q], hb = c4[q + 1], hc = c4[q + 2], hd = c4[q + 3];
      a0 += ha.x * w[q].x + ha.y * w[q].y + ha.z * w[q].z + ha.w * w[q].w;
      a1 += hb.x * w[q + 1].x + hb.y * w[q + 1].y + hb.z * w[q + 1].z + hb.w * w[q + 1].w;
      a2 += hc.x * w[q + 2].x + hc.y * w[q + 2].y + hc.z * w[q + 2].z + hc.w * w[q + 2].w;
      a3 += hd.x * w[q + 3].x + hd.y * w[q + 3].y + hd.z * w[q + 3].z + hd.w * w[q + 3].w;
    }
    out[i] = (a0 + a1) + (a2 + a3);
  }
#pragma unroll
  for (int i = 0; i < 16; i++) predio[(vbase + s * 16 + i) * 64 + j] = out[i];
}

extern "C" void kernel_launch(void* const* d_in, const int* in_sizes, int n_in,
                              void* d_out, int out_size, void* d_ws, size_t ws_size,
                              hipStream_t stream) {
  const float* x        = (const float*)d_in[0];
  const float* conv1_w  = (const float*)d_in[1];
  const float* conv1_b  = (const float*)d_in[2];
  const float* conv2_w  = (const float*)d_in[3];
  const float* conv2_b  = (const float*)d_in[4];
  const float* codebook = (const float*)d_in[5];
  const float* gru_w_ih = (const float*)d_in[6];
  const float* gru_w_hh = (const float*)d_in[7];
  const float* gru_b_ih = (const float*)d_in[8];
  const float* gru_b_hh = (const float*)d_in[9];
  const float* proj_w   = (const float*)d_in[10];
  const float* proj_b   = (const float*)d_in[11];

  float* out = (float*)d_out;
  float* quant = out + QOFF;     // y1 lives here first, then quant_z
  float* predz = out + POFF;     // z, then ctx, then pred (each dead before overwrite)
  float* codes_f = out + COFF;

  float* ws = (float*)d_ws;      // needs ~620 KB
  float* cnorm = ws;
  float* PC = ws + PCOFF;        // [128][192]
  int* codes_i = (int*)(ws + CIOFF);

  cnorm_kernel<<<1, 128, 0, stream>>>(codebook, cnorm);
  conv1_kernel<<<4096, 256, 0, stream>>>(x, conv1_w, conv1_b, quant /* = y1 */);
  conv2_kernel<<<2048, 256, 0, stream>>>(quant /* y1 */, conv2_w, conv2_b, predz /* = z */);
  quant_kernel<<<2048, 256, 0, stream>>>(predz /* z */, codebook, cnorm, quant, codes_f, codes_i);
  pc_kernel<<<128, 192, 0, stream>>>(codebook, gru_w_ih, gru_b_ih, PC);
  gru_kernel<<<64, 128, 0, stream>>>(PC, codes_i, gru_w_hh, gru_b_hh, predz /* = ctx */);
  proj_kernel<<<2048, 256, 0, stream>>>(proj_w, proj_b, predz /* ctx -> pred in place */);
}

// Round 6
// 1425.774 us; speedup vs baseline: 1.4199x; 1.4199x over previous
//
#include <hip/hip_runtime.h>

// Problem constants
#define NB   64      // batch
#define CIN  8
#define LIN  8192
#define L1N  4096    // conv1 out length
#define T2   2048    // conv2 out length (time steps)
#define ENC  64
#define NK   128     // codebook size
#define CD   64      // code dim
#define G3   192     // 3*ENC

// d_out layout (floats): quant_z [64*2048*64] | pred [64*2048*64] | codes [64*2048]
#define QOFF 0
#define POFF 8388608
#define COFF 16777216

// ws layout (floats): cnorm[128] @0 | PC[128*192] @128 | codes_i[131072] (int) @24704
#define PCOFF 128
#define CIOFF 24704

typedef _Float16 half2v __attribute__((ext_vector_type(2)));

__device__ __forceinline__ float sigf(float x) {
  float e = __builtin_amdgcn_exp2f(-1.4426950408889634f * x);
  return __builtin_amdgcn_rcpf(1.0f + e);
}
__device__ __forceinline__ float tanhf_fast(float x) {
  float e = __builtin_amdgcn_exp2f(2.8853900817779268f * x);
  return 1.0f - 2.0f * __builtin_amdgcn_rcpf(e + 1.0f);
}
__device__ __forceinline__ float rlane(float v, int k) {
  return __int_as_float(__builtin_amdgcn_readlane(__float_as_int(v), k));
}
__device__ __forceinline__ half2v as_h2(float v) { return __builtin_bit_cast(half2v, v); }

// ---------------- K0: prep = codebook norms (block 128) + PC table (blocks 0..127) ----------------
__global__ __launch_bounds__(192) void prep_kernel(const float* __restrict__ cb,
                                                   const float* __restrict__ w_ih,
                                                   const float* __restrict__ b_ih,
                                                   float* __restrict__ cnorm,
                                                   float* __restrict__ PC) {
  int blk = blockIdx.x;
  int j = threadIdx.x;
  if (blk == 128) {
    if (j < 128) {
      const float4* r = (const float4*)(cb + j * CD);
      float s0 = 0.f, s1 = 0.f, s2 = 0.f, s3 = 0.f;
#pragma unroll
      for (int q = 0; q < 16; q += 4) {
        float4 a = r[q], b = r[q + 1], cc = r[q + 2], d = r[q + 3];
        s0 += a.x * a.x + a.y * a.y + a.z * a.z + a.w * a.w;
        s1 += b.x * b.x + b.y * b.y + b.z * b.z + b.w * b.w;
        s2 += cc.x * cc.x + cc.y * cc.y + cc.z * cc.z + cc.w * cc.w;
        s3 += d.x * d.x + d.y * d.y + d.z * d.z + d.w * d.w;
      }
      cnorm[j] = (s0 + s1) + (s2 + s3);
    }
    return;
  }
  int c = blk;
  const float4* wp = (const float4*)(w_ih + j * ENC);
  const float4* cp = (const float4*)(cb + c * CD);
  float a0 = b_ih[j], a1 = 0.f, a2 = 0.f, a3 = 0.f;
#pragma unroll
  for (int q = 0; q < 16; q += 4) {
    float4 w0 = wp[q], c0 = cp[q];
    float4 w1 = wp[q + 1], c1 = cp[q + 1];
    float4 w2 = wp[q + 2], c2 = cp[q + 2];
    float4 w3 = wp[q + 3], c3 = cp[q + 3];
    a0 += w0.x * c0.x + w0.y * c0.y + w0.z * c0.z + w0.w * c0.w;
    a1 += w1.x * c1.x + w1.y * c1.y + w1.z * c1.z + w1.w * c1.w;
    a2 += w2.x * c2.x + w2.y * c2.y + w2.z * c2.z + w2.w * c2.w;
    a3 += w3.x * c3.x + w3.y * c3.y + w3.z * c3.z + w3.w * c3.w;
  }
  PC[c * G3 + j] = (a0 + a1) + (a2 + a3);
}

// ---------------- K1: conv1 + relu  (x[64,8,8192] -> y1[64,32,4096]) ----------------
__global__ __launch_bounds__(256) void conv1_kernel(const float* __restrict__ x,
                                                    const float* __restrict__ w1,
                                                    const float* __restrict__ b1,
                                                    float* __restrict__ y1) {
  __shared__ float sw[1280];      // [co][ci][k] natural
  __shared__ float sx[8][136];    // u = xi - (2*t0-2), u in [0,131)
  int b = blockIdx.x >> 6;
  int t0 = (blockIdx.x & 63) * 64;
  int tid = threadIdx.x;
  for (int i = tid; i < 1280; i += 256) sw[i] = w1[i];
  const float* xb = x + b * CIN * LIN;
  for (int i = tid; i < 8 * 131; i += 256) {
    int ci = i / 131, u = i - ci * 131;
    int xi = 2 * t0 - 2 + u;
    sx[ci][u] = ((unsigned)xi < (unsigned)LIN) ? xb[ci * LIN + xi] : 0.f;
  }
  __syncthreads();
  int co = tid >> 3, tg = tid & 7;
  float bias = b1[co];
  float acc[8];
#pragma unroll
  for (int j = 0; j < 8; j++) acc[j] = bias;
#pragma unroll
  for (int ci = 0; ci < 8; ci++) {
    float xv[20];
    const float2* s2 = (const float2*)(&sx[ci][16 * tg]);
#pragma unroll
    for (int q = 0; q < 10; q++) {
      float2 v = s2[q];
      xv[2 * q] = v.x; xv[2 * q + 1] = v.y;
    }
    float wk[5];
#pragma unroll
    for (int k = 0; k < 5; k++) wk[k] = sw[(co * 8 + ci) * 5 + k];
#pragma unroll
    for (int j = 0; j < 8; j++) {
#pragma unroll
      for (int k = 0; k < 5; k++) acc[j] = fmaf(xv[2 * j + k], wk[k], acc[j]);
    }
  }
  float4* outp = (float4*)(y1 + (b * 32 + co) * L1N + t0 + tg * 8);
  float4 o0, o1;
  o0.x = fmaxf(acc[0], 0.f); o0.y = fmaxf(acc[1], 0.f);
  o0.z = fmaxf(acc[2], 0.f); o0.w = fmaxf(acc[3], 0.f);
  o1.x = fmaxf(acc[4], 0.f); o1.y = fmaxf(acc[5], 0.f);
  o1.z = fmaxf(acc[6], 0.f); o1.w = fmaxf(acc[7], 0.f);
  outp[0] = o0; outp[1] = o1;
}

// ---------------- K2: conv2 + relu, transposed out (y1[64,32,4096] -> z[64,2048,64]) ----------------
__global__ void conv2_kernel(const float* __restrict__ y1, const float* __restrict__ w2,
                             const float* __restrict__ b2, float* __restrict__ z) {
  __shared__ float sw[32 * 5 * 64];
  __shared__ float sx[32][136];
  int b = blockIdx.x >> 5;
  int t0 = (blockIdx.x & 31) * 64;
  int tid = threadIdx.x;
  for (int i = tid; i < 32 * 5 * 64; i += 256) {
    int co = i & 63, r = i >> 6;
    sw[i] = w2[co * 160 + r];
  }
  for (int i = tid; i < 32 * 136; i += 256) {
    int ci = i / 136, u = i - ci * 136;
    int xi = 2 * t0 - 4 + u;
    float v = 0.f;
    if (xi >= 0 && xi < L1N) v = y1[(b * 32 + ci) * L1N + xi];
    sx[ci][u] = v;
  }
  __syncthreads();
  int co = tid & 63, ts = tid >> 6;
  float acc[16];
  float bb = b2[co];
#pragma unroll
  for (int i = 0; i < 16; i++) acc[i] = bb;
  for (int ci = 0; ci < 32; ci++) {
    float xr[40];
    const float4* sx4 = (const float4*)(&sx[ci][32 * ts]);
#pragma unroll
    for (int q = 0; q < 10; q++) {
      float4 v = sx4[q];
      xr[4 * q] = v.x; xr[4 * q + 1] = v.y; xr[4 * q + 2] = v.z; xr[4 * q + 3] = v.w;
    }
    float wk[5];
#pragma unroll
    for (int k = 0; k < 5; k++) wk[k] = sw[(ci * 5 + k) * 64 + co];
#pragma unroll
    for (int i = 0; i < 16; i++) {
#pragma unroll
      for (int k = 0; k < 5; k++) acc[i] = fmaf(xr[2 * i + k + 2], wk[k], acc[i]);
    }
  }
#pragma unroll
  for (int i = 0; i < 16; i++) {
    int t = t0 + ts * 16 + i;
    z[(b * T2 + t) * ENC + co] = fmaxf(acc[i], 0.f);
  }
}

// ---------------- K3: VQ argmin + gather (fp32 exact — codes must be exact) ----------------
__global__ __attribute__((amdgpu_flat_work_group_size(256, 256), amdgpu_waves_per_eu(1, 2)))
void quant_kernel(const float* __restrict__ z,
                  const float* __restrict__ cb,
                  const float* __restrict__ cnorm,
                  float* __restrict__ quant,
                  float* __restrict__ codes_f,
                  int* __restrict__ codes_i) {
  int tid = threadIdx.x, lane = tid & 63, wave = tid >> 6;
  int vbase = blockIdx.x * 64 + wave * 16;
  float4 ca[16], cq[16];
  const float4* pa = (const float4*)(cb + lane * CD);
  const float4* pb = (const float4*)(cb + (64 + lane) * CD);
#define LQ(q) ca[q] = pa[q]; cq[q] = pb[q];
  LQ(0) LQ(1) LQ(2) LQ(3) LQ(4) LQ(5) LQ(6) LQ(7)
  LQ(8) LQ(9) LQ(10) LQ(11) LQ(12) LQ(13) LQ(14) LQ(15)
#undef LQ
  float cn0 = cnorm[lane], cn1 = cnorm[64 + lane];
  for (int v = vbase; v < vbase + 16; v++) {
    float zz = z[v * 64 + lane];
    float d00 = 0.f, d01 = 0.f, d02 = 0.f, d03 = 0.f;
    float d10 = 0.f, d11 = 0.f, d12 = 0.f, d13 = 0.f;
#define DQ(q) { \
    float h0 = rlane(zz, 4 * (q) + 0); float h1 = rlane(zz, 4 * (q) + 1); \
    float h2 = rlane(zz, 4 * (q) + 2); float h3 = rlane(zz, 4 * (q) + 3); \
    d00 = fmaf(ca[q].x, h0, d00); d01 = fmaf(ca[q].y, h1, d01); \
    d02 = fmaf(ca[q].z, h2, d02); d03 = fmaf(ca[q].w, h3, d03); \
    d10 = fmaf(cq[q].x, h0, d10); d11 = fmaf(cq[q].y, h1, d11); \
    d12 = fmaf(cq[q].z, h2, d12); d13 = fmaf(cq[q].w, h3, d13); }
    DQ(0) DQ(1) DQ(2) DQ(3) DQ(4) DQ(5) DQ(6) DQ(7)
    DQ(8) DQ(9) DQ(10) DQ(11) DQ(12) DQ(13) DQ(14) DQ(15)
#undef DQ
    float s0 = cn0 - 2.f * ((d00 + d01) + (d02 + d03));
    float s1 = cn1 - 2.f * ((d10 + d11) + (d12 + d13));
    float sc; int idx;
    if (s1 < s0) { sc = s1; idx = 64 + lane; } else { sc = s0; idx = lane; }
#pragma unroll
    for (int m = 1; m < 64; m <<= 1) {
      float os = __shfl_xor(sc, m);
      int oi = __shfl_xor(idx, m);
      if (os < sc || (os == sc && oi < idx)) { sc = os; idx = oi; }
    }
    if (lane == 0) { codes_f[v] = (float)idx; codes_i[v] = idx; }
    quant[v * 64 + lane] = cb[idx * 64 + lane];
  }
}

// ---------------- K5: GRU scan — single wave/batch, fp16-dot2 matvec (fits VGPR grant) ----------------
// Lane j holds W_hh rows j / 64+j / 128+j as f16 PAIRS (96 VGPRs, under the ~132 grant ->
// no AGPR spill round-trips). h stays fp32; packed to f16 pairs once per step (2 shfl +
// cvt), broadcast via 32 readlanes, consumed by v_dot2_f32_f16 (fp32 accumulate; f16xf16
// products are exact in fp32 -> error = input quantization only, ~1e-3 on gh).
__global__ __attribute__((amdgpu_flat_work_group_size(64, 64), amdgpu_waves_per_eu(1, 1)))
void gru_kernel(const float* __restrict__ PC,
                const int* __restrict__ codes_i,
                const float* __restrict__ w_hh,
                const float* __restrict__ b_hh,
                float* __restrict__ ctx) {
  int b = blockIdx.x;
  int lane = threadIdx.x;
  half2v wr[32], wz[32], wn[32];
  {
    const float2* p0 = (const float2*)(w_hh + lane * ENC);
    const float2* p1 = (const float2*)(w_hh + (64 + lane) * ENC);
    const float2* p2 = (const float2*)(w_hh + (128 + lane) * ENC);
#pragma unroll
    for (int m = 0; m < 32; m++) {
      float2 a = p0[m]; wr[m] = (half2v){(_Float16)a.x, (_Float16)a.y};
      float2 c = p1[m]; wz[m] = (half2v){(_Float16)c.x, (_Float16)c.y};
      float2 d = p2[m]; wn[m] = (half2v){(_Float16)d.x, (_Float16)d.y};
    }
  }
  float br = b_hh[lane], bz = b_hh[64 + lane], bn = b_hh[128 + lane];
  const int* cp = codes_i + b * T2;
  float hreg = 0.f;
  int lane2a = 2 * lane, lane2b = 2 * lane + 1;  // shuffle sources (loop-invariant)
  int cA = cp[2];
  float xr0, xz0, xn0, xr1, xz1, xn1;
  {
    const float* g = PC + cp[0] * G3;
    xr0 = g[lane]; xz0 = g[64 + lane]; xn0 = g[128 + lane];
    g = PC + cp[1] * G3;
    xr1 = g[lane]; xz1 = g[64 + lane]; xn1 = g[128 + lane];
  }
  float* cbase = ctx + (size_t)b * T2 * ENC + lane;
#pragma unroll 1
  for (int t = 0; t < T2; t++) {
    const float* g = PC + cA * G3;                  // x for step t+2
    float xr2 = g[lane], xz2 = g[64 + lane], xn2 = g[128 + lane];
    int tn = t + 3; if (tn > T2 - 1) tn = T2 - 1;
    cA = cp[tn];
    // pack h into f16 pairs: lane m (m<32) holds (h[2m], h[2m+1])
    float he = __shfl(hreg, lane2a);
    float ho = __shfl(hreg, lane2b);
    half2v hp2 = {(_Float16)he, (_Float16)ho};
    float hpk = __builtin_bit_cast(float, hp2);
    float fr0 = br, fr1 = 0.f, fr2 = 0.f, fr3 = 0.f;
    float fz0 = bz, fz1 = 0.f, fz2 = 0.f, fz3 = 0.f;
    float fn0 = bn, fn1 = 0.f, fn2 = 0.f, fn3 = 0.f;
#define MV(q) { \
    float s0 = rlane(hpk, 4 * (q) + 0); float s1 = rlane(hpk, 4 * (q) + 1); \
    float s2 = rlane(hpk, 4 * (q) + 2); float s3 = rlane(hpk, 4 * (q) + 3); \
    fr0 = __builtin_amdgcn_fdot2(wr[4 * (q) + 0], as_h2(s0), fr0, false); \
    fr1 = __builtin_amdgcn_fdot2(wr[4 * (q) + 1], as_h2(s1), fr1, false); \
    fr2 = __builtin_amdgcn_fdot2(wr[4 * (q) + 2], as_h2(s2), fr2, false); \
    fr3 = __builtin_amdgcn_fdot2(wr[4 * (q) + 3], as_h2(s3), fr3, false); \
    fz0 = __builtin_amdgcn_fdot2(wz[4 * (q) + 0], as_h2(s0), fz0, false); \
    fz1 = __builtin_amdgcn_fdot2(wz[4 * (q) + 1], as_h2(s1), fz1, false); \
    fz2 = __builtin_amdgcn_fdot2(wz[4 * (q) + 2], as_h2(s2), fz2, false); \
    fz3 = __builtin_amdgcn_fdot2(wz[4 * (q) + 3], as_h2(s3), fz3, false); \
    fn0 = __builtin_amdgcn_fdot2(wn[4 * (q) + 0], as_h2(s0), fn0, false); \
    fn1 = __builtin_amdgcn_fdot2(wn[4 * (q) + 1], as_h2(s1), fn1, false); \
    fn2 = __builtin_amdgcn_fdot2(wn[4 * (q) + 2], as_h2(s2), fn2, false); \
    fn3 = __builtin_amdgcn_fdot2(wn[4 * (q) + 3], as_h2(s3), fn3, false); }
    MV(0) MV(1) MV(2) MV(3) MV(4) MV(5) MV(6) MV(7)
#undef MV
    float ghr = (fr0 + fr1) + (fr2 + fr3);
    float ghz = (fz0 + fz1) + (fz2 + fz3);
    float ghn = (fn0 + fn1) + (fn2 + fn3);
    float r = sigf(xr0 + ghr);
    float zg = sigf(xz0 + ghz);
    float n = tanhf_fast(xn0 + r * ghn);
    hreg = fmaf(zg, hreg - n, n);
    cbase[(size_t)t * ENC] = hreg;
    xr0 = xr1; xz0 = xz1; xn0 = xn1;
    xr1 = xr2; xz1 = xz2; xn1 = xn2;
  }
}

// ---------------- K6: pred = ctx @ proj_w^T + proj_b (in-place on the ctx/pred slot) ----------------
__global__ void proj_kernel(const float* __restrict__ proj_w, const float* __restrict__ proj_b,
                            float* __restrict__ predio) {
  __shared__ float sc[64 * 64];
  int vbase = blockIdx.x * 64;
  int tid = threadIdx.x;
  int j = tid & 63, s = tid >> 6;
  for (int i = tid; i < 4096; i += 256) sc[i] = predio[vbase * 64 + i];
  __syncthreads();
  float4 w[16];
  const float4* wr = (const float4*)(proj_w + j * ENC);
#pragma unroll
  for (int q = 0; q < 16; q++) w[q] = wr[q];
  float bias = proj_b[j];
  float out[16];
#pragma unroll 4
  for (int i = 0; i < 16; i++) {
    const float4* c4 = (const float4*)(&sc[(s * 16 + i) * 64]);
    float a0 = bias, a1 = 0.f, a2 = 0.f, a3 = 0.f;
#pragma unroll
    for (int q = 0; q < 16; q += 4) {
      float4 ha = c4[q], hb = c4[q + 1], hc = c4[q + 2], hd = c4[q + 3];
      a0 += ha.x * w[q].x + ha.y * w[q].y + ha.z * w[q].z + ha.w * w[q].w;
      a1 += hb.x * w[q + 1].x + hb.y * w[q + 1].y + hb.z * w[q + 1].z + hb.w * w[q + 1].w;
      a2 += hc.x * w[q + 2].x + hc.y * w[q + 2].y + hc.z * w[q + 2].z + hc.w * w[q + 2].w;
      a3 += hd.x * w[q + 3].x + hd.y * w[q + 3].y + hd.z * w[q + 3].z + hd.w * w[q + 3].w;
    }
    out[i] = (a0 + a1) + (a2 + a3);
  }
#pragma unroll
  for (int i = 0; i < 16; i++) predio[(vbase + s * 16 + i) * 64 + j] = out[i];
}

extern "C" void kernel_launch(void* const* d_in, const int* in_sizes, int n_in,
                              void* d_out, int out_size, void* d_ws, size_t ws_size,
                              hipStream_t stream) {
  const float* x        = (const float*)d_in[0];
  const float* conv1_w  = (const float*)d_in[1];
  const float* conv1_b  = (const float*)d_in[2];
  const float* conv2_w  = (const float*)d_in[3];
  const float* conv2_b  = (const float*)d_in[4];
  const float* codebook = (const float*)d_in[5];
  const float* gru_w_ih = (const float*)d_in[6];
  const float* gru_w_hh = (const float*)d_in[7];
  const float* gru_b_ih = (const float*)d_in[8];
  const float* gru_b_hh = (const float*)d_in[9];
  const float* proj_w   = (const float*)d_in[10];
  const float* proj_b   = (const float*)d_in[11];

  float* out = (float*)d_out;
  float* quant = out + QOFF;     // y1 lives here first, then quant_z
  float* predz = out + POFF;     // z, then ctx, then pred (each dead before overwrite)
  float* codes_f = out + COFF;

  float* ws = (float*)d_ws;      // needs ~620 KB
  float* cnorm = ws;
  float* PC = ws + PCOFF;        // [128][192]
  int* codes_i = (int*)(ws + CIOFF);

  prep_kernel<<<129, 192, 0, stream>>>(codebook, gru_w_ih, gru_b_ih, cnorm, PC);
  conv1_kernel<<<4096, 256, 0, stream>>>(x, conv1_w, conv1_b, quant /* = y1 */);
  conv2_kernel<<<2048, 256, 0, stream>>>(quant /* y1 */, conv2_w, conv2_b, predz /* = z */);
  quant_kernel<<<2048, 256, 0, stream>>>(predz /* z */, codebook, cnorm, quant, codes_f, codes_i);
  gru_kernel<<<64, 64, 0, stream>>>(PC, codes_i, gru_w_hh, gru_b_hh, predz /* = ctx */);
  proj_kernel<<<2048, 256, 0, stream>>>(proj_w, proj_b, predz /* ctx -> pred in place */);
}